// Round 1
// baseline (820.364 us; speedup 1.0000x reference)
//
#include <hip/hip_runtime.h>

// out[b,i] = exp(l-d) / (exp(l-d) + rowsum - exp(l))
//          = e*s / (e*(s-1) + rowsum),  e = exp(l), s = exp(-d)
//
// 4096 rows x 32000 cols fp32. One block per row, 320 threads,
// 25 float4 per thread kept in registers across the reduction
// (single global read of logits, single write of out).

#define COLS 32000
#define BLOCK 320
#define VPT 25  // (32000/4) / 320 float4 per thread

__global__ __launch_bounds__(BLOCK) void soft_margin_softmax_kernel(
    const float* __restrict__ logits,
    const float* __restrict__ dist,
    float* __restrict__ out) {
    const int row = blockIdx.x;
    const int tid = threadIdx.x;

    const float4* __restrict__ lrow =
        reinterpret_cast<const float4*>(logits + (size_t)row * COLS);
    float4* __restrict__ orow =
        reinterpret_cast<float4*>(out + (size_t)row * COLS);

    const float s = __expf(-dist[0]);

    float4 e[VPT];
    float local = 0.0f;
#pragma unroll
    for (int i = 0; i < VPT; ++i) {
        float4 l = lrow[tid + i * BLOCK];
        float4 ev;
        ev.x = __expf(l.x);
        ev.y = __expf(l.y);
        ev.z = __expf(l.z);
        ev.w = __expf(l.w);
        e[i] = ev;
        local += (ev.x + ev.y) + (ev.z + ev.w);
    }

    // wave64 reduction
#pragma unroll
    for (int off = 32; off > 0; off >>= 1)
        local += __shfl_down(local, off, 64);

    __shared__ float wsum[BLOCK / 64];
    const int wid = tid >> 6;
    const int lane = tid & 63;
    if (lane == 0) wsum[wid] = local;
    __syncthreads();

    const float rowsum =
        (wsum[0] + wsum[1]) + (wsum[2] + wsum[3]) + wsum[4];
    const float sm1 = s - 1.0f;

#pragma unroll
    for (int i = 0; i < VPT; ++i) {
        float4 ev = e[i];
        float4 o;
        o.x = __fdividef(ev.x * s, ev.x * sm1 + rowsum);
        o.y = __fdividef(ev.y * s, ev.y * sm1 + rowsum);
        o.z = __fdividef(ev.z * s, ev.z * sm1 + rowsum);
        o.w = __fdividef(ev.w * s, ev.w * sm1 + rowsum);
        orow[tid + i * BLOCK] = o;
    }
}

extern "C" void kernel_launch(void* const* d_in, const int* in_sizes, int n_in,
                              void* d_out, int out_size, void* d_ws, size_t ws_size,
                              hipStream_t stream) {
    const float* logits = (const float*)d_in[0];
    const float* dist = (const float*)d_in[1];
    float* out = (float*)d_out;
    const int rows = out_size / COLS;  // 4096
    soft_margin_softmax_kernel<<<rows, BLOCK, 0, stream>>>(logits, dist, out);
}